// Round 9
// baseline (177.683 us; speedup 1.0000x reference)
//
#include <hip/hip_runtime.h>
#include <hip/hip_fp16.h>

#define BATCH   1024
#define IN      1024
#define OUT     40960
#define KF      7
#define BT      8            // batch rows per block: one 8-row fp16 table
#define NO      16           // output column groups per thread (OTILE 4096)
#define THREADS 256
#define OTILE   (THREADS * NO)   // 4096 outputs per block
#define CHUNKS  (OUT / 64)       // 640 chunks of 64 consecutive outputs

// Workspace:
//   pmeta : uint2 [CHUNKS][KF][64]  {x = idx<<4 (LDS byte off), y = f32 val bits}
//   xpk   : f16   [BATCH/8][IN][8]  x rounded fp16, 8 batch rows per 16-B granule
#define PMETA_BYTES ((size_t)CHUNKS * KF * 64 * 8)        // 2,293,760
#define XPK_BYTES   ((size_t)(BATCH / 8) * IN * 8 * 2)    // 2,097,152

// Round-9: ledger rules out gather granule / meta volume / stage volume /
// store drain (4us) / occupancy / ws persistence. Residual ~11us over the
// zero-overlap pipe sum lives in unprobed terms: (a) write-channel aliasing --
// 4-KB row chunks at 160-KB stride (== 0 mod ~32-KB interleave period) put a
// block's whole 32 KB on one channel class; (b) VGPR-capped gather ILP at
// launch_bounds(256,8). This version: OTILE=4096 (NO=16), grid (10,128)=1280
// blocks = exactly 5/CU. Per-row write footprint 4->16 KB (4 channel classes),
// stage traffic 84->21 MB, launch_bounds(256,5) -> ~96 VGPRs so all 7 gather
// b128s + meta double-buffer stay in flight. r6's debugged meta prefetch kept
// (group stride = 4 chunks * KF*64 records).

__global__ __launch_bounds__(THREADS)
void repack_kernel(const float* __restrict__ x, const float* __restrict__ vals,
                   const int* __restrict__ idx,
                   uint2* __restrict__ pmeta, __half* __restrict__ xpk)
{
    const int gid = blockIdx.x * THREADS + threadIdx.x;
    if (blockIdx.x < 512) {
        // ---- part A: x[1024][1024] f32 -> xpk[g][i][8] f16 ----
        const int g = gid >> 10;        // batch group 0..127
        const int i = gid & 1023;       // column
        const float* xb = x + (size_t)g * 8 * IN + i;
        union { __half h[8]; float4 f; } u;
#pragma unroll
        for (int r = 0; r < 8; ++r) u.h[r] = __float2half_rn(xb[(size_t)r * IN]);
        *(float4*)&xpk[(size_t)gid * 8] = u.f;   // coalesced 16-B store
    } else {
        // ---- part B: idx/vals [OUT][KF] -> pmeta[CHUNKS][KF][64] ----
        const int t2 = gid - 512 * THREADS;      // 0 .. 286719
        const int c  = t2 / (KF * 64);
        const int r  = t2 % (KF * 64);
        const int k  = r >> 6;
        const int l  = r & 63;
        const size_t src = (size_t)(c * 64 + l) * KF + k;
        uint2 m;
        m.x = (unsigned)(idx[src] << 4);         // byte offset into xs table
        m.y = __float_as_uint(vals[src]);
        pmeta[t2] = m;
    }
}

__global__ __launch_bounds__(THREADS, 5)
void sparse_proj(const uint2* __restrict__ pmeta, const __half* __restrict__ xpk,
                 float* __restrict__ y)
{
    // one 8-row table: xs[i*16B] = rows b0 .. b0+7 (fp16)
    __shared__ __align__(16) __half xs[IN * 8];   // 16 KB

    const int t     = threadIdx.x;
    const int b0    = blockIdx.y * BT;
    const int obase = blockIdx.x * OTILE + t;

    // ---- stage: straight 16 KB copy, already fp16 + gather-layout ----
    {
        const float4* src = (const float4*)(xpk + (size_t)blockIdx.y * IN * 8);
        float4* dst = (float4*)xs;
#pragma unroll
        for (int r = 0; r < 4; ++r) dst[t + r * THREADS] = src[t + r * THREADS];
    }
    __syncthreads();

    const int w    = t >> 6;
    const int lane = t & 63;

    // Group no's chunk: c = blockIdx.x*64 + no*4 + w.
    // Record offset from mbase (in uint2): no * 4 * (KF*64) + k*64.
    const uint2* mbase = pmeta + (size_t)(blockIdx.x * 64 + w) * (KF * 64) + lane;

    // double-buffered meta registers (statically indexed after unroll)
    uint2 mc[KF], mn[KF];
#pragma unroll
    for (int k = 0; k < KF; ++k) mc[k] = mbase[k * 64];   // group 0

#pragma unroll
    for (int no = 0; no < NO; ++no) {
        // ---- prefetch NEXT group's meta before this group's stores, so the
        // next waitcnt does not force draining younger stores (r6 lesson) ----
        if (no + 1 < NO) {
#pragma unroll
            for (int k = 0; k < KF; ++k)
                mn[k] = mbase[(size_t)(no + 1) * 4 * (KF * 64) + k * 64];
        }

        float acc[BT];
#pragma unroll
        for (int r = 0; r < BT; ++r) acc[r] = 0.0f;

#pragma unroll
        for (int k = 0; k < KF; ++k) {
            const unsigned off = mc[k].x;            // i*16
            const float v = __uint_as_float(mc[k].y);
            const float4 g0 = *(const float4*)((const char*)xs + off); // 8 rows
            const __half2 a0 = *(const __half2*)&g0.x;
            const __half2 a1 = *(const __half2*)&g0.y;
            const __half2 a2 = *(const __half2*)&g0.z;
            const __half2 a3 = *(const __half2*)&g0.w;
            acc[0] = fmaf(v, __low2float(a0),  acc[0]);
            acc[1] = fmaf(v, __high2float(a0), acc[1]);
            acc[2] = fmaf(v, __low2float(a1),  acc[2]);
            acc[3] = fmaf(v, __high2float(a1), acc[3]);
            acc[4] = fmaf(v, __low2float(a2),  acc[4]);
            acc[5] = fmaf(v, __high2float(a2), acc[5]);
            acc[6] = fmaf(v, __low2float(a3),  acc[6]);
            acc[7] = fmaf(v, __high2float(a3), acc[7]);
        }

        // ---- store this group now (plain stores: retire at L2). Per row the
        // block writes 16 KB contiguous across the 16 groups -> 4 channel
        // classes per block instead of 1. ----
        const int o = obase + no * THREADS;
#pragma unroll
        for (int r = 0; r < BT; ++r) {
            y[(size_t)(b0 + r) * OUT + o] = acc[r];
        }

        // rotate meta buffers (register moves, statically unrolled)
#pragma unroll
        for (int k = 0; k < KF; ++k) mc[k] = mn[k];
    }
}

extern "C" void kernel_launch(void* const* d_in, const int* in_sizes, int n_in,
                              void* d_out, int out_size, void* d_ws, size_t ws_size,
                              hipStream_t stream) {
    const float* x    = (const float*)d_in[0];   // [1024, 1024] fp32
    const float* vals = (const float*)d_in[1];   // [40960, 7]  fp32
    const int*   idx  = (const int*)d_in[2];     // [40960, 7]  int32
    float*       y    = (float*)d_out;           // [1024, 40960] fp32

    uint2*  pmeta = (uint2*)d_ws;
    __half* xpk   = (__half*)((char*)d_ws + PMETA_BYTES);

    // 512 blocks for xpk (131072 threads) + 1120 blocks for pmeta (286720)
    repack_kernel<<<dim3(512 + 1120), dim3(THREADS), 0, stream>>>(
        x, vals, idx, pmeta, xpk);

    dim3 grid(OUT / OTILE, BATCH / BT);          // (10, 128) = 1280 blocks, 5/CU
    sparse_proj<<<grid, dim3(THREADS), 0, stream>>>(pmeta, xpk, y);
}